// Round 12
// baseline (255.726 us; speedup 1.0000x reference)
//
#include <hip/hip_runtime.h>
#include <hip/hip_bf16.h>
#include <math.h>

#define NB 4
#define NL 512
#define ND 128
#define KSTR 136  // 272B row stride

typedef __attribute__((ext_vector_type(8))) short bf16x8;
typedef __attribute__((ext_vector_type(4))) float f32x4;
typedef __attribute__((ext_vector_type(16))) float f32x16;

__device__ __forceinline__ short f2bf(float f) {
  union { float f; unsigned u; } un; un.f = f;
  unsigned r = un.u + 0x7FFFu + ((un.u >> 16) & 1u);  // RNE
  return (short)(r >> 16);
}

// GELU via sigmoid approximation: gelu(h) ~= h * sigmoid(1.702 h).
__device__ __forceinline__ float gelu_fast(float h) {
  const float e = exp2f(h * -2.4554572f);
  return h * __builtin_amdgcn_rcpf(1.0f + e);
}

// prep: gamma-folded bf16 w1 [n][k]; beta-folded b1; col-sums s1 of the bf16
// weights (exact cancellation in the LN fold); notpad; 1/atom_num.
__global__ void unimol_prep(const float* __restrict__ w1, const float* __restrict__ ln_g,
                            const float* __restrict__ ln_b, const float* __restrict__ b1,
                            const int* __restrict__ nodes,
                            short* __restrict__ w1f, float* __restrict__ b1p,
                            float* __restrict__ s1p,
                            float* __restrict__ npad, float* __restrict__ inva) {
  const int tid = threadIdx.x;
  for (int idx = tid; idx < ND * ND; idx += 256) {
    const int k = idx >> 7, n = idx & (ND - 1);
    w1f[n * ND + k] = f2bf(w1[idx] * ln_g[k]);
  }
  __syncthreads();
  if (tid < ND) {
    float s = b1[tid];
    for (int k = 0; k < ND; ++k) s = fmaf(ln_b[k], w1[k * ND + tid], s);
    b1p[tid] = s;
    float cs = 0.f;
    for (int k = 0; k < ND; ++k) {
      union { unsigned u; float f; } v; v.u = ((unsigned)(unsigned short)w1f[tid * ND + k]) << 16;
      cs += v.f;
    }
    s1p[tid] = cs;
  }
  for (int j = tid; j < NB * NL; j += 256) npad[j] = (nodes[j] != 0) ? 1.0f : 0.0f;
  const int wv = tid >> 6, lane = tid & 63;
  if (wv < NB) {
    float s = 0.f;
    for (int j = lane; j < NL; j += 64) s += (nodes[wv * NL + j] != 0) ? 1.0f : 0.0f;
    #pragma unroll
    for (int m = 1; m <= 32; m <<= 1) s += __shfl_xor(s, m);
    if (lane == 0) inva[wv] = 1.0f / s;
  }
}

// 32x32x16 MFMA: each wave computes 32 m-rows/iter -> w1 LDS tile read once
// per 32 rows (DS traffic halved vs 16x16), MFMA issue count halved.
// LN stays folded past the MFMA (raw-x fragments + rs/mu correction after).
__global__ __launch_bounds__(512, 2) void unimol_coord_head(
    const float* __restrict__ x, const float* __restrict__ coord,
    const float* __restrict__ w2, const float* __restrict__ b2,
    const short* __restrict__ w1f, const float* __restrict__ b1pw,
    const float* __restrict__ s1pw,
    const float* __restrict__ npadw, const float* __restrict__ invw,
    float* __restrict__ out)
{
  __shared__ __align__(16) short w1T[ND * KSTR];
  __shared__ float b1p[ND];
  __shared__ float w2s[ND];
  __shared__ float s1s[ND];
  __shared__ float notpad[NL];
  __shared__ float coord_s[NL * 3];
  __shared__ float red[2][16];

  const int blk = blockIdx.x;
  const int bb = blk >> 8;
  const int pair = blk & 255;
  const int tid = threadIdx.x;
  const int row = tid >> 8;           // which l-row this wave group owns
  const int lrow = 2 * pair + row;
  const int ltid = tid & 255;

  for (int t = tid; t < (ND * ND) / 8; t += 512) {
    const int r = t >> 4, cg = (t & 15) << 3;
    *reinterpret_cast<bf16x8*>(&w1T[r * KSTR + cg]) =
        *reinterpret_cast<const bf16x8*>(&w1f[r * ND + cg]);
  }
  if (tid < ND) { b1p[tid] = b1pw[tid]; w2s[tid] = w2[tid]; s1s[tid] = s1pw[tid]; }
  for (int j = tid; j < NL; j += 512) notpad[j] = npadw[bb * NL + j];
  for (int j = tid; j < NL * 3; j += 512) coord_s[j] = coord[bb * (NL * 3) + j];
  __syncthreads();

  const int lane = tid & 63;
  const int wv4 = (tid >> 6) & 3;   // wave index within this row's group of 4
  const int a = lane & 31;          // A-row / B-col (n) / D-col (n) within tile
  const int kh = lane >> 5;         // k-half within a K=16 step
  const bool live = (notpad[lrow] != 0.0f);

  if (live) {
    float b1r[4], w2r[4], s1r[4];
    #pragma unroll
    for (int nb = 0; nb < 4; ++nb) {
      b1r[nb] = b1p[32 * nb + a];
      w2r[nb] = w2s[32 * nb + a];
      s1r[nb] = s1s[32 * nb + a];
    }
    const float b2c = b2[0] * (1.0f / 32.0f);   // m shared by 32 lanes now
    float s0 = 0.f, sx = 0.f, sy = 0.f, sz = 0.f;
    const size_t xbase = (size_t)(bb * NL + lrow) * (NL * ND);

    for (int it = 0; it < 4; ++it) {
      const int mbase = (it << 7) + (wv4 << 5);   // 128 m per block-iter, 32 per wave
      const float* xr = x + xbase + (size_t)(mbase + a) * ND + 8 * kh;

      float sum = 0.f, sq = 0.f;
      f32x16 acc[4];
      #pragma unroll
      for (int nb = 0; nb < 4; ++nb)
        #pragma unroll
        for (int i = 0; i < 16; ++i) acc[nb][i] = 0.f;

      #pragma unroll
      for (int kc = 0; kc < 8; ++kc) {
        const f32x4 v0 = *reinterpret_cast<const f32x4*>(xr + 16 * kc);
        const f32x4 v1 = *reinterpret_cast<const f32x4*>(xr + 16 * kc + 4);
        // stats (tree-shaped to keep the chain short)
        sum += ((v0[0] + v0[1]) + (v0[2] + v0[3])) + ((v1[0] + v1[1]) + (v1[2] + v1[3]));
        sq  += (fmaf(v0[0], v0[0], v0[1] * v0[1]) + fmaf(v0[2], v0[2], v0[3] * v0[3])) +
               (fmaf(v1[0], v1[0], v1[1] * v1[1]) + fmaf(v1[2], v1[2], v1[3] * v1[3]));
        // raw x -> bf16 A-fragment for this K=16 step
        union { bf16x8 v; __hip_bfloat162 h[4]; } u;
        float2 t0, t1, t2, t3;
        t0.x = v0[0]; t0.y = v0[1]; t1.x = v0[2]; t1.y = v0[3];
        t2.x = v1[0]; t2.y = v1[1]; t3.x = v1[2]; t3.y = v1[3];
        u.h[0] = __float22bfloat162_rn(t0); u.h[1] = __float22bfloat162_rn(t1);
        u.h[2] = __float22bfloat162_rn(t2); u.h[3] = __float22bfloat162_rn(t3);
        const bf16x8 af = u.v;
        #pragma unroll
        for (int nb = 0; nb < 4; ++nb) {
          const bf16x8 bf = *reinterpret_cast<const bf16x8*>(
              &w1T[(32 * nb + a) * KSTR + 16 * kc + 8 * kh]);
          acc[nb] = __builtin_amdgcn_mfma_f32_32x32x16_bf16(af, bf, acc[nb], 0, 0, 0);
        }
      }

      // finish stats: lane kh=0 has cols {16kc..+7}, kh=1 the rest -> xor 32
      sum += __shfl_xor(sum, 32);
      sq  += __shfl_xor(sq, 32);
      const float mu = sum * (1.0f / ND);
      const float rs = rsqrtf(fmaf(-mu, mu, sq * (1.0f / ND)) + 1e-5f);
      const float nmr = -rs * mu;   // lane holds stats of row a (both halves)

      // epilogue over D: col(n)=32nb+a, row m = (reg&3)+8*(reg>>2)+4*kh
      #pragma unroll
      for (int reg = 0; reg < 16; ++reg) {
        const int mrow = (reg & 3) + 8 * (reg >> 2) + 4 * kh;
        const float rsm  = __shfl(rs, mrow);    // stats of row mrow live in lane mrow
        const float nmrm = __shfl(nmr, mrow);
        float pm = 0.f;
        #pragma unroll
        for (int nb = 0; nb < 4; ++nb) {
          const float h = fmaf(acc[nb][reg], rsm, fmaf(s1r[nb], nmrm, b1r[nb]));
          pm = fmaf(gelu_fast(h), w2r[nb], pm);
        }
        const int m = mbase + mrow;
        const float av = (pm + b2c) * notpad[m];
        s0 += av;
        sx = fmaf(av, coord_s[3 * m + 0], sx);
        sy = fmaf(av, coord_s[3 * m + 1], sy);
        sz = fmaf(av, coord_s[3 * m + 2], sz);
      }
    }

    #pragma unroll
    for (int m = 1; m <= 32; m <<= 1) {
      s0 += __shfl_xor(s0, m); sx += __shfl_xor(sx, m);
      sy += __shfl_xor(sy, m); sz += __shfl_xor(sz, m);
    }
    if (lane == 0) {
      red[row][wv4 * 4 + 0] = s0; red[row][wv4 * 4 + 1] = sx;
      red[row][wv4 * 4 + 2] = sy; red[row][wv4 * 4 + 3] = sz;
    }
  } else if (lane == 0) {
    red[row][wv4 * 4 + 0] = 0.f; red[row][wv4 * 4 + 1] = 0.f;
    red[row][wv4 * 4 + 2] = 0.f; red[row][wv4 * 4 + 3] = 0.f;
  }
  __syncthreads();

  if (ltid == 0) {
    const float cx = coord_s[3 * lrow + 0], cy = coord_s[3 * lrow + 1], cz = coord_s[3 * lrow + 2];
    float* o = out + (bb * NL + lrow) * 3;
    if (live) {
      const float S0 = red[row][0] + red[row][4] + red[row][8] + red[row][12];
      const float SX = red[row][1] + red[row][5] + red[row][9] + red[row][13];
      const float SY = red[row][2] + red[row][6] + red[row][10] + red[row][14];
      const float SZ = red[row][3] + red[row][7] + red[row][11] + red[row][15];
      const float ia = invw[bb];
      o[0] = cx + (SX - S0 * cx) * ia;
      o[1] = cy + (SY - S0 * cy) * ia;
      o[2] = cz + (SZ - S0 * cz) * ia;
    } else {
      o[0] = cx; o[1] = cy; o[2] = cz;
    }
  }
}

extern "C" void kernel_launch(void* const* d_in, const int* in_sizes, int n_in,
                              void* d_out, int out_size, void* d_ws, size_t ws_size,
                              hipStream_t stream) {
  const float* x     = (const float*)d_in[0];
  const float* coord = (const float*)d_in[1];
  const int*   nodes = (const int*)d_in[2];
  const float* ln_g  = (const float*)d_in[3];
  const float* ln_b  = (const float*)d_in[4];
  const float* w1    = (const float*)d_in[5];
  const float* b1    = (const float*)d_in[6];
  const float* w2    = (const float*)d_in[7];
  const float* b2    = (const float*)d_in[8];
  float* out = (float*)d_out;

  short* w1f  = (short*)d_ws;                       // 32768 B
  float* b1p  = (float*)((char*)d_ws + 32768);      // 512 B
  float* s1p  = (float*)((char*)d_ws + 33280);      // 512 B
  float* npad = (float*)((char*)d_ws + 33792);      // 8192 B
  float* inva = (float*)((char*)d_ws + 41984);      // 16 B

  hipLaunchKernelGGL(unimol_prep, dim3(1), dim3(256), 0, stream,
                     w1, ln_g, ln_b, b1, nodes, w1f, b1p, s1p, npad, inva);
  hipLaunchKernelGGL(unimol_coord_head, dim3(NB * NL / 2), dim3(512), 0, stream,
                     x, coord, w2, b2, w1f, b1p, s1p, npad, inva, out);
}

// Round 13
// 229.811 us; speedup vs baseline: 1.1128x; 1.1128x over previous
//
#include <hip/hip_runtime.h>
#include <hip/hip_bf16.h>
#include <math.h>

#define NB 4
#define NL 512
#define ND 128

typedef __attribute__((ext_vector_type(8))) short bf16x8;
typedef __attribute__((ext_vector_type(4))) float f32x4;

__device__ __forceinline__ short f2bf(float f) {
  union { float f; unsigned u; } un; un.f = f;
  unsigned r = un.u + 0x7FFFu + ((un.u >> 16) & 1u);  // RNE
  return (short)(r >> 16);
}

// GELU via sigmoid approximation: gelu(h) ~= h * sigmoid(1.702 h).
__device__ __forceinline__ float gelu_fast(float h) {
  const float e = exp2f(h * -2.4554572f);
  return h * __builtin_amdgcn_rcpf(1.0f + e);
}

// prep: gamma-folded bf16 w1 [n][k]; beta-folded b1; col-sums s1 of the bf16
// weights; notpad; 1/atom_num.
__global__ void unimol_prep(const float* __restrict__ w1, const float* __restrict__ ln_g,
                            const float* __restrict__ ln_b, const float* __restrict__ b1,
                            const int* __restrict__ nodes,
                            short* __restrict__ w1f, float* __restrict__ b1p,
                            float* __restrict__ s1p,
                            float* __restrict__ npad, float* __restrict__ inva) {
  const int tid = threadIdx.x;
  for (int idx = tid; idx < ND * ND; idx += 256) {
    const int k = idx >> 7, n = idx & (ND - 1);
    w1f[n * ND + k] = f2bf(w1[idx] * ln_g[k]);
  }
  __syncthreads();
  if (tid < ND) {
    float s = b1[tid];
    for (int k = 0; k < ND; ++k) s = fmaf(ln_b[k], w1[k * ND + tid], s);
    b1p[tid] = s;
    float cs = 0.f;
    for (int k = 0; k < ND; ++k) {
      union { unsigned u; float f; } v; v.u = ((unsigned)(unsigned short)w1f[tid * ND + k]) << 16;
      cs += v.f;
    }
    s1p[tid] = cs;
  }
  for (int j = tid; j < NB * NL; j += 256) npad[j] = (nodes[j] != 0) ? 1.0f : 0.0f;
  const int wv = tid >> 6, lane = tid & 63;
  if (wv < NB) {
    float s = 0.f;
    for (int j = lane; j < NL; j += 64) s += (nodes[wv * NL + j] != 0) ? 1.0f : 0.0f;
    #pragma unroll
    for (int m = 1; m <= 32; m <<= 1) s += __shfl_xor(s, m);
    if (lane == 0) inva[wv] = 1.0f / s;
  }
}

// n-split register-B kernel: 256 threads = 4 waves = 2 m-halves x 2 n-halves.
// Each wave owns 64 n-columns whose B-fragments live ENTIRELY in registers
// (16 x bf16x8 = 64 VGPR, loaded once from L2-resident w1f) -> zero per-iter
// LDS reads. gelu-sum over n is linear, so n-half waves accumulate partial
// s0/sx/sy/sz merged by the existing block reduction. Per-iter body = r11.
__global__ __launch_bounds__(256, 2) void unimol_coord_head(
    const float* __restrict__ x, const float* __restrict__ coord,
    const float* __restrict__ w2, const float* __restrict__ b2,
    const short* __restrict__ w1f, const float* __restrict__ b1pw,
    const float* __restrict__ s1pw,
    const float* __restrict__ npadw, const float* __restrict__ invw,
    float* __restrict__ out)
{
  __shared__ float notpad[NL];
  __shared__ float coord_s[NL * 3];
  __shared__ float red[16];

  const int blk = blockIdx.x;
  const int bb = blk >> 9;
  const int lrow = blk & (NL - 1);
  const int tid = threadIdx.x;

  if (npadw[bb * NL + lrow] == 0.0f) {   // pad row: output = coord
    if (tid < 3) out[(bb * NL + lrow) * 3 + tid] = coord[(bb * NL + lrow) * 3 + tid];
    return;
  }

  for (int j = tid; j < NL; j += 256) notpad[j] = npadw[bb * NL + j];
  for (int j = tid; j < NL * 3; j += 256) coord_s[j] = coord[bb * (NL * 3) + j];
  __syncthreads();

  const int lane = tid & 63;
  const int wv = tid >> 6;
  const int mhalf = wv >> 1;        // which 256-row m-half this wave covers
  const int nhalf = wv & 1;         // which 64-col n-half this wave covers
  const int c = lane & 15;          // A-row / D-col within tile
  const int g = lane >> 4;          // k-group

  // ---- B fragments in registers: 4 nt x 4 ks, cols 64*nhalf + 16*nt + c ----
  bf16x8 bfr[4][4];
  float b1r[4], w2r[4], s1r[4];
  #pragma unroll
  for (int nt = 0; nt < 4; ++nt) {
    const int col = 64 * nhalf + 16 * nt + c;
    #pragma unroll
    for (int ks = 0; ks < 4; ++ks)
      bfr[nt][ks] = *reinterpret_cast<const bf16x8*>(&w1f[col * ND + 32 * ks + 8 * g]);
    b1r[nt] = b1pw[col];
    w2r[nt] = w2[col];
    s1r[nt] = s1pw[col];
  }
  const float b2c = b2[0] * (1.0f / 32.0f);  // 2 n-half waves x 16 c-lanes per m

  float s0 = 0.f, sx = 0.f, sy = 0.f, sz = 0.f;
  const size_t xbase = (size_t)(bb * NL + lrow) * (NL * ND);
  const float* xr = x + xbase + (size_t)(mhalf * 256 + c) * ND + 8 * g;

  for (int it = 0; it < 16; ++it, xr += 16 * ND) {
    const int mbase = mhalf * 256 + (it << 4);
    f32x4 xv[8];
    #pragma unroll
    for (int ks = 0; ks < 4; ++ks) {
      xv[2 * ks]     = *reinterpret_cast<const f32x4*>(xr + 32 * ks);
      xv[2 * ks + 1] = *reinterpret_cast<const f32x4*>(xr + 32 * ks + 4);
    }

    // raw x -> bf16 A-fragments (LN folded past MFMA)
    bf16x8 af[4];
    #pragma unroll
    for (int ks = 0; ks < 4; ++ks) {
      union { bf16x8 v; __hip_bfloat162 h[4]; } u;
      float2 t0, t1, t2, t3;
      t0.x = xv[2 * ks][0];     t0.y = xv[2 * ks][1];
      t1.x = xv[2 * ks][2];     t1.y = xv[2 * ks][3];
      t2.x = xv[2 * ks + 1][0]; t2.y = xv[2 * ks + 1][1];
      t3.x = xv[2 * ks + 1][2]; t3.y = xv[2 * ks + 1][3];
      u.h[0] = __float22bfloat162_rn(t0); u.h[1] = __float22bfloat162_rn(t1);
      u.h[2] = __float22bfloat162_rn(t2); u.h[3] = __float22bfloat162_rn(t3);
      af[ks] = u.v;
    }

    // LN stats (independent chain, overlaps MFMA block)
    float sum = 0.f, sq = 0.f;
    #pragma unroll
    for (int q = 0; q < 8; ++q) {
      #pragma unroll
      for (int j = 0; j < 4; ++j) { const float e = xv[q][j]; sum += e; sq = fmaf(e, e, sq); }
    }
    sum += __shfl_xor(sum, 16); sum += __shfl_xor(sum, 32);
    sq  += __shfl_xor(sq, 16);  sq  += __shfl_xor(sq, 32);
    const float mu = sum * (1.0f / ND);
    const float rs = rsqrtf(fmaf(-mu, mu, sq * (1.0f / ND)) + 1e-5f);
    const float nrsmu = -rs * mu;

    f32x4 acc[4];
    #pragma unroll
    for (int nt = 0; nt < 4; ++nt) acc[nt] = (f32x4){0.f, 0.f, 0.f, 0.f};
    #pragma unroll
    for (int ks = 0; ks < 4; ++ks) {
      #pragma unroll
      for (int nt = 0; nt < 4; ++nt)
        acc[nt] = __builtin_amdgcn_mfma_f32_16x16x32_bf16(af[ks], bfr[nt][ks], acc[nt], 0, 0, 0);
    }

    // post-MFMA LN correction + GELU + w2 dot (partial over this n-half)
    float p[4] = {0.f, 0.f, 0.f, 0.f};
    #pragma unroll
    for (int nt = 0; nt < 4; ++nt) {
      const float tmp = fmaf(s1r[nt], nrsmu, b1r[nt]);
      #pragma unroll
      for (int i = 0; i < 4; ++i) {
        const float h = fmaf(acc[nt][i], rs, tmp);
        p[i] = fmaf(gelu_fast(h), w2r[nt], p[i]);
      }
    }
    #pragma unroll
    for (int i = 0; i < 4; ++i) {
      const int m = mbase + 4 * g + i;
      const float a = (p[i] + b2c) * notpad[m];
      s0 += a;
      sx = fmaf(a, coord_s[3 * m + 0], sx);
      sy = fmaf(a, coord_s[3 * m + 1], sy);
      sz = fmaf(a, coord_s[3 * m + 2], sz);
    }
  }

  #pragma unroll
  for (int m = 1; m <= 32; m <<= 1) {
    s0 += __shfl_xor(s0, m); sx += __shfl_xor(sx, m);
    sy += __shfl_xor(sy, m); sz += __shfl_xor(sz, m);
  }
  if (lane == 0) {
    red[wv * 4 + 0] = s0; red[wv * 4 + 1] = sx;
    red[wv * 4 + 2] = sy; red[wv * 4 + 3] = sz;
  }
  __syncthreads();
  if (tid == 0) {
    const float S0 = red[0] + red[4] + red[8] + red[12];
    const float SX = red[1] + red[5] + red[9] + red[13];
    const float SY = red[2] + red[6] + red[10] + red[14];
    const float SZ = red[3] + red[7] + red[11] + red[15];
    const float ia = invw[bb];
    const float cx = coord_s[3 * lrow + 0], cy = coord_s[3 * lrow + 1], cz = coord_s[3 * lrow + 2];
    float* o = out + (bb * NL + lrow) * 3;
    o[0] = cx + (SX - S0 * cx) * ia;
    o[1] = cy + (SY - S0 * cy) * ia;
    o[2] = cz + (SZ - S0 * cz) * ia;
  }
}

extern "C" void kernel_launch(void* const* d_in, const int* in_sizes, int n_in,
                              void* d_out, int out_size, void* d_ws, size_t ws_size,
                              hipStream_t stream) {
  const float* x     = (const float*)d_in[0];
  const float* coord = (const float*)d_in[1];
  const int*   nodes = (const int*)d_in[2];
  const float* ln_g  = (const float*)d_in[3];
  const float* ln_b  = (const float*)d_in[4];
  const float* w1    = (const float*)d_in[5];
  const float* b1    = (const float*)d_in[6];
  const float* w2    = (const float*)d_in[7];
  const float* b2    = (const float*)d_in[8];
  float* out = (float*)d_out;

  short* w1f  = (short*)d_ws;                       // 32768 B
  float* b1p  = (float*)((char*)d_ws + 32768);      // 512 B
  float* s1p  = (float*)((char*)d_ws + 33280);      // 512 B
  float* npad = (float*)((char*)d_ws + 33792);      // 8192 B
  float* inva = (float*)((char*)d_ws + 41984);      // 16 B

  hipLaunchKernelGGL(unimol_prep, dim3(1), dim3(256), 0, stream,
                     w1, ln_g, ln_b, b1, nodes, w1f, b1p, s1p, npad, inva);
  hipLaunchKernelGGL(unimol_coord_head, dim3(NB * NL), dim3(256), 0, stream,
                     x, coord, w2, b2, w1f, b1p, s1p, npad, inva, out);
}

// Round 14
// 184.550 us; speedup vs baseline: 1.3857x; 1.2453x over previous
//
#include <hip/hip_runtime.h>
#include <hip/hip_bf16.h>
#include <math.h>

#define NB 4
#define NL 512
#define ND 128

typedef __attribute__((ext_vector_type(8))) short bf16x8;
typedef __attribute__((ext_vector_type(4))) float f32x4;

__device__ __forceinline__ short f2bf(float f) {
  union { float f; unsigned u; } un; un.f = f;
  unsigned r = un.u + 0x7FFFu + ((un.u >> 16) & 1u);  // RNE
  return (short)(r >> 16);
}

// GELU via sigmoid approximation: gelu(h) ~= h * sigmoid(1.702 h).
__device__ __forceinline__ float gelu_fast(float h) {
  const float e = exp2f(h * -2.4554572f);
  return h * __builtin_amdgcn_rcpf(1.0f + e);
}

// prep: gamma-folded bf16 w1 [n][k]; beta-folded b1; col-sums s1 of the bf16
// weights; notpad; 1/atom_num.
__global__ void unimol_prep(const float* __restrict__ w1, const float* __restrict__ ln_g,
                            const float* __restrict__ ln_b, const float* __restrict__ b1,
                            const int* __restrict__ nodes,
                            short* __restrict__ w1f, float* __restrict__ b1p,
                            float* __restrict__ s1p,
                            float* __restrict__ npad, float* __restrict__ inva) {
  const int tid = threadIdx.x;
  for (int idx = tid; idx < ND * ND; idx += 256) {
    const int k = idx >> 7, n = idx & (ND - 1);
    w1f[n * ND + k] = f2bf(w1[idx] * ln_g[k]);
  }
  __syncthreads();
  if (tid < ND) {
    float s = b1[tid];
    for (int k = 0; k < ND; ++k) s = fmaf(ln_b[k], w1[k * ND + tid], s);
    b1p[tid] = s;
    float cs = 0.f;
    for (int k = 0; k < ND; ++k) {
      union { unsigned u; float f; } v; v.u = ((unsigned)(unsigned short)w1f[tid * ND + k]) << 16;
      cs += v.f;
    }
    s1p[tid] = cs;
  }
  for (int j = tid; j < NB * NL; j += 256) npad[j] = (nodes[j] != 0) ? 1.0f : 0.0f;
  const int wv = tid >> 6, lane = tid & 63;
  if (wv < NB) {
    float s = 0.f;
    for (int j = lane; j < NL; j += 64) s += (nodes[wv * NL + j] != 0) ? 1.0f : 0.0f;
    #pragma unroll
    for (int m = 1; m <= 32; m <<= 1) s += __shfl_xor(s, m);
    if (lane == 0) inva[wv] = 1.0f / s;
  }
}

// Async-DMA kernel: x tiles stream into an LDS double-buffer via
// global_load_lds (DMA stays in flight during compute -> HBM duty cycle ~1),
// B entirely in registers (n-split across wave pairs), LN folded past MFMA.
// LDS rows are XOR-swizzled (byte ^= (row&7)<<4) via pre-swizzled GLOBAL
// source addresses (linear DMA dest) so A ds_read_b128 is bank-conflict-free.
__global__ __launch_bounds__(256, 1) void unimol_coord_head(
    const float* __restrict__ x, const float* __restrict__ coord,
    const float* __restrict__ w2, const float* __restrict__ b2,
    const short* __restrict__ w1f, const float* __restrict__ b1pw,
    const float* __restrict__ s1pw,
    const float* __restrict__ npadw, const float* __restrict__ invw,
    float* __restrict__ out)
{
  __shared__ __align__(16) float xbuf[2][32 * ND];   // 2 x 16KB tiles (swizzled rows)
  __shared__ float notpad[NL];
  __shared__ float coord_s[NL * 3];
  __shared__ float red[16];

  const int blk = blockIdx.x;
  const int bb = blk >> 9;
  const int lrow = blk & (NL - 1);
  const int tid = threadIdx.x;

  if (npadw[bb * NL + lrow] == 0.0f) {   // pad row: output = coord (block-uniform)
    if (tid < 3) out[(bb * NL + lrow) * 3 + tid] = coord[(bb * NL + lrow) * 3 + tid];
    return;
  }

  for (int j = tid; j < NL; j += 256) notpad[j] = npadw[bb * NL + j];
  for (int j = tid; j < NL * 3; j += 256) coord_s[j] = coord[bb * (NL * 3) + j];

  const int lane = tid & 63;
  const int wv = tid >> 6;
  const int mgrp = wv >> 1;   // which 16-row group of the 32-row tile
  const int nhalf = wv & 1;   // which 64-col n-half
  const int c = lane & 15;    // A-row / D-col within 16x16 tile
  const int g = lane >> 4;    // k-group

  // B fragments + epilogue consts in registers (loaded once, L2-resident)
  bf16x8 bfr[4][4];
  float b1r[4], w2r[4], s1r[4];
  #pragma unroll
  for (int nt = 0; nt < 4; ++nt) {
    const int col = 64 * nhalf + 16 * nt + c;
    #pragma unroll
    for (int ks = 0; ks < 4; ++ks)
      bfr[nt][ks] = *reinterpret_cast<const bf16x8*>(&w1f[col * ND + 32 * ks + 8 * g]);
    b1r[nt] = b1pw[col];
    w2r[nt] = w2[col];
    s1r[nt] = s1pw[col];
  }
  const float b2c = b2[0] * (1.0f / 32.0f);  // 32 partial contributions per m

  // l-row's x slice: contiguous 512KB/2... (512 rows x 512B = 256KB)
  const char* xl = (const char*)(x + (size_t)(bb * NL + lrow) * (NL * ND));

  // DMA one 32-row (16KB) tile t into xbuf[b]; linear LDS dest, source
  // pre-swizzled so lds[row][col] = x[row][col ^ ((row&7)<<4)].
#define STAGE(b, t)                                                              \
  do {                                                                           \
    const char* src_ = xl + (size_t)(t) * 16384;                                 \
    _Pragma("unroll")                                                            \
    for (int q_ = 0; q_ < 4; ++q_) {                                             \
      const unsigned off_ = (unsigned)(wv * 4096 + q_ * 1024 + lane * 16);       \
      const unsigned soff_ = off_ ^ (((off_ >> 9) & 7u) << 4);                   \
      __builtin_amdgcn_global_load_lds(                                          \
          (const __attribute__((address_space(1))) void*)(src_ + soff_),         \
          (__attribute__((address_space(3))) void*)((char*)&xbuf[(b)][0] + wv * 4096 + q_ * 1024), \
          16, 0, 0);                                                             \
    }                                                                            \
  } while (0)

  STAGE(0, 0);
  __syncthreads();   // drains DMA (vmcnt) + joins staging

  float s0 = 0.f, sx = 0.f, sy = 0.f, sz = 0.f;
  const int r = 16 * mgrp + c;               // row within the 32-row tile
  const unsigned swz = ((unsigned)(c & 7)) << 4;

  #pragma unroll 1
  for (int it = 0; it < 16; ++it) {
    const int cur = it & 1;
    if (it < 15) STAGE(cur ^ 1, it + 1);     // DMA next tile; in flight all iter

    // A-fragments from swizzled LDS (conflict-free per 8-lane phase)
    const char* base = (const char*)&xbuf[cur][r * ND];
    f32x4 xv[8];
    #pragma unroll
    for (int ks = 0; ks < 4; ++ks) {
      const unsigned o1 = ((unsigned)(128 * ks + 32 * g)) ^ swz;
      const unsigned o2 = ((unsigned)(128 * ks + 32 * g + 16)) ^ swz;
      xv[2 * ks]     = *reinterpret_cast<const f32x4*>(base + o1);
      xv[2 * ks + 1] = *reinterpret_cast<const f32x4*>(base + o2);
    }

    // raw x -> bf16 A-fragments (LN folded past MFMA)
    bf16x8 af[4];
    #pragma unroll
    for (int ks = 0; ks < 4; ++ks) {
      union { bf16x8 v; __hip_bfloat162 h[4]; } u;
      float2 t0, t1, t2, t3;
      t0.x = xv[2 * ks][0];     t0.y = xv[2 * ks][1];
      t1.x = xv[2 * ks][2];     t1.y = xv[2 * ks][3];
      t2.x = xv[2 * ks + 1][0]; t2.y = xv[2 * ks + 1][1];
      t3.x = xv[2 * ks + 1][2]; t3.y = xv[2 * ks + 1][3];
      u.h[0] = __float22bfloat162_rn(t0); u.h[1] = __float22bfloat162_rn(t1);
      u.h[2] = __float22bfloat162_rn(t2); u.h[3] = __float22bfloat162_rn(t3);
      af[ks] = u.v;
    }

    // LN stats (independent chain; overlaps MFMA block)
    float sum = 0.f, sq = 0.f;
    #pragma unroll
    for (int q = 0; q < 8; ++q) {
      #pragma unroll
      for (int j = 0; j < 4; ++j) { const float e = xv[q][j]; sum += e; sq = fmaf(e, e, sq); }
    }
    sum += __shfl_xor(sum, 16); sum += __shfl_xor(sum, 32);
    sq  += __shfl_xor(sq, 16);  sq  += __shfl_xor(sq, 32);
    const float mu = sum * (1.0f / ND);
    const float rs = rsqrtf(fmaf(-mu, mu, sq * (1.0f / ND)) + 1e-5f);
    const float nrsmu = -rs * mu;

    f32x4 acc[4];
    #pragma unroll
    for (int nt = 0; nt < 4; ++nt) acc[nt] = (f32x4){0.f, 0.f, 0.f, 0.f};
    #pragma unroll
    for (int ks = 0; ks < 4; ++ks) {
      #pragma unroll
      for (int nt = 0; nt < 4; ++nt)
        acc[nt] = __builtin_amdgcn_mfma_f32_16x16x32_bf16(af[ks], bfr[nt][ks], acc[nt], 0, 0, 0);
    }

    // post-MFMA LN correction + GELU + w2 dot (partial over this n-half)
    float p[4] = {0.f, 0.f, 0.f, 0.f};
    #pragma unroll
    for (int nt = 0; nt < 4; ++nt) {
      const float tmp = fmaf(s1r[nt], nrsmu, b1r[nt]);
      #pragma unroll
      for (int i = 0; i < 4; ++i) {
        const float h = fmaf(acc[nt][i], rs, tmp);
        p[i] = fmaf(gelu_fast(h), w2r[nt], p[i]);
      }
    }
    const int mbase = 32 * it + 16 * mgrp;
    #pragma unroll
    for (int i = 0; i < 4; ++i) {
      const int m = mbase + 4 * g + i;       // D-layout row
      const float a = (p[i] + b2c) * notpad[m];
      s0 += a;
      sx = fmaf(a, coord_s[3 * m + 0], sx);
      sy = fmaf(a, coord_s[3 * m + 1], sy);
      sz = fmaf(a, coord_s[3 * m + 2], sz);
    }

    __syncthreads();   // drains next-tile DMA + releases xbuf[cur] for overwrite
  }

  #pragma unroll
  for (int m = 1; m <= 32; m <<= 1) {
    s0 += __shfl_xor(s0, m); sx += __shfl_xor(sx, m);
    sy += __shfl_xor(sy, m); sz += __shfl_xor(sz, m);
  }
  if (lane == 0) {
    red[wv * 4 + 0] = s0; red[wv * 4 + 1] = sx;
    red[wv * 4 + 2] = sy; red[wv * 4 + 3] = sz;
  }
  __syncthreads();
  if (tid == 0) {
    const float S0 = red[0] + red[4] + red[8] + red[12];
    const float SX = red[1] + red[5] + red[9] + red[13];
    const float SY = red[2] + red[6] + red[10] + red[14];
    const float SZ = red[3] + red[7] + red[11] + red[15];
    const float ia = invw[bb];
    const float cx = coord_s[3 * lrow + 0], cy = coord_s[3 * lrow + 1], cz = coord_s[3 * lrow + 2];
    float* o = out + (bb * NL + lrow) * 3;
    o[0] = cx + (SX - S0 * cx) * ia;
    o[1] = cy + (SY - S0 * cy) * ia;
    o[2] = cz + (SZ - S0 * cz) * ia;
  }
#undef STAGE
}

extern "C" void kernel_launch(void* const* d_in, const int* in_sizes, int n_in,
                              void* d_out, int out_size, void* d_ws, size_t ws_size,
                              hipStream_t stream) {
  const float* x     = (const float*)d_in[0];
  const float* coord = (const float*)d_in[1];
  const int*   nodes = (const int*)d_in[2];
  const float* ln_g  = (const float*)d_in[3];
  const float* ln_b  = (const float*)d_in[4];
  const float* w1    = (const float*)d_in[5];
  const float* b1    = (const float*)d_in[6];
  const float* w2    = (const float*)d_in[7];
  const float* b2    = (const float*)d_in[8];
  float* out = (float*)d_out;

  short* w1f  = (short*)d_ws;                       // 32768 B
  float* b1p  = (float*)((char*)d_ws + 32768);      // 512 B
  float* s1p  = (float*)((char*)d_ws + 33280);      // 512 B
  float* npad = (float*)((char*)d_ws + 33792);      // 8192 B
  float* inva = (float*)((char*)d_ws + 41984);      // 16 B

  hipLaunchKernelGGL(unimol_prep, dim3(1), dim3(256), 0, stream,
                     w1, ln_g, ln_b, b1, nodes, w1f, b1p, s1p, npad, inva);
  hipLaunchKernelGGL(unimol_coord_head, dim3(NB * NL), dim3(256), 0, stream,
                     x, coord, w2, b2, w1f, b1p, s1p, npad, inva, out);
}